// Round 2
// baseline (125.482 us; speedup 1.0000x reference)
//
#include <hip/hip_runtime.h>

// CrossNet collapsed analytically:
//   a_j = x0 . w_j          (3 dots, single pass over x0)
//   s0 = a0
//   s1 = (1+s0)*a1 + B0.w1
//   s2 = (1+s0+s1)*a2 + (B0+B1).w2
//   out = x0 * (1+s0+s1+s2) + (B0+B1+B2)
// t1 = B0.w1, t2 = (B0+B1).w2, Bsum are row-independent -> per-wave prologue.
// One wave per row-group of 4 rows; W rows + Bsum live in registers for the
// whole wave; rows double-buffered (prefetch r+1 under reduce/write of r).
// Streaming x0/out via nontemporal load/store. 64 MiB read + 64 MiB write.

#define CN_BATCH 16384
#define CN_DIM   1024

#define WAVES_PER_BLOCK 4
#define ROWS_PER_WAVE   4
#define ROWS_PER_BLOCK  (WAVES_PER_BLOCK * ROWS_PER_WAVE)   // 16

// clang ext vector: accepted by __builtin_nontemporal_{load,store},
// same codegen (global_load_dwordx4 / global_store_dwordx4) as float4.
typedef float f32x4 __attribute__((ext_vector_type(4)));

__global__ __launch_bounds__(256, 4) void
crossnet_kernel(const float* __restrict__ x0,
                const float* __restrict__ W,
                const float* __restrict__ B,
                float* __restrict__ out)
{
    const int tid  = threadIdx.x;
    const int wave = tid >> 6;
    const int lane = tid & 63;
    const int off0 = lane * 4;          // lane's 16B-aligned column offset

    // ---- per-wave prologue: hoist W rows, Bsum, and B-derived scalars ----
    f32x4 w0[4], w1[4], w2[4], bs[4];
    float t1 = 0.f, t2 = 0.f;
#pragma unroll
    for (int c = 0; c < 4; ++c) {
        const int off = c * 256 + off0;
        w0[c] = *reinterpret_cast<const f32x4*>(W + 0 * CN_DIM + off);
        w1[c] = *reinterpret_cast<const f32x4*>(W + 1 * CN_DIM + off);
        w2[c] = *reinterpret_cast<const f32x4*>(W + 2 * CN_DIM + off);
        const f32x4 b0 = *reinterpret_cast<const f32x4*>(B + 0 * CN_DIM + off);
        const f32x4 b1 = *reinterpret_cast<const f32x4*>(B + 1 * CN_DIM + off);
        const f32x4 b2 = *reinterpret_cast<const f32x4*>(B + 2 * CN_DIM + off);
        bs[c] = b0 + b1 + b2;
        t1 = fmaf(b0.x, w1[c].x, t1); t1 = fmaf(b0.y, w1[c].y, t1);
        t1 = fmaf(b0.z, w1[c].z, t1); t1 = fmaf(b0.w, w1[c].w, t1);
        t2 = fmaf(b0.x + b1.x, w2[c].x, t2); t2 = fmaf(b0.y + b1.y, w2[c].y, t2);
        t2 = fmaf(b0.z + b1.z, w2[c].z, t2); t2 = fmaf(b0.w + b1.w, w2[c].w, t2);
    }
#pragma unroll
    for (int o = 1; o < 64; o <<= 1) {
        t1 += __shfl_xor(t1, o, 64);
        t2 += __shfl_xor(t2, o, 64);
    }

    // ---- row loop: 4 rows per wave, software-pipelined ----
    const size_t row0 = ((size_t)blockIdx.x * WAVES_PER_BLOCK + wave) * ROWS_PER_WAVE;
    const float* __restrict__ xr = x0 + row0 * (size_t)CN_DIM;

    f32x4 cur[4], nxt[4];
#pragma unroll
    for (int c = 0; c < 4; ++c)
        cur[c] = __builtin_nontemporal_load(
            reinterpret_cast<const f32x4*>(xr + c * 256 + off0));

#pragma unroll
    for (int r = 0; r < ROWS_PER_WAVE; ++r) {
        // prefetch next row while we reduce/write the current one
        if (r + 1 < ROWS_PER_WAVE) {
#pragma unroll
            for (int c = 0; c < 4; ++c)
                nxt[c] = __builtin_nontemporal_load(
                    reinterpret_cast<const f32x4*>(
                        xr + (size_t)(r + 1) * CN_DIM + c * 256 + off0));
        }

        // three dot-product partials in one pass (independent accumulators)
        float a0 = 0.f, a1 = 0.f, a2 = 0.f;
#pragma unroll
        for (int c = 0; c < 4; ++c) {
            a0 = fmaf(cur[c].x, w0[c].x, a0); a0 = fmaf(cur[c].y, w0[c].y, a0);
            a0 = fmaf(cur[c].z, w0[c].z, a0); a0 = fmaf(cur[c].w, w0[c].w, a0);
            a1 = fmaf(cur[c].x, w1[c].x, a1); a1 = fmaf(cur[c].y, w1[c].y, a1);
            a1 = fmaf(cur[c].z, w1[c].z, a1); a1 = fmaf(cur[c].w, w1[c].w, a1);
            a2 = fmaf(cur[c].x, w2[c].x, a2); a2 = fmaf(cur[c].y, w2[c].y, a2);
            a2 = fmaf(cur[c].z, w2[c].z, a2); a2 = fmaf(cur[c].w, w2[c].w, a2);
        }

        // three parallel 6-step butterflies (one reduction phase, not three layers)
#pragma unroll
        for (int o = 1; o < 64; o <<= 1) {
            a0 += __shfl_xor(a0, o, 64);
            a1 += __shfl_xor(a1, o, 64);
            a2 += __shfl_xor(a2, o, 64);
        }

        const float s0 = a0;
        const float s1 = fmaf(1.f + s0, a1, t1);
        const float s2 = fmaf(1.f + s0 + s1, a2, t2);
        const float cf = 1.f + s0 + s1 + s2;

        float* __restrict__ orow = out + (row0 + (size_t)r) * CN_DIM;
#pragma unroll
        for (int c = 0; c < 4; ++c) {
            f32x4 o;
            o.x = fmaf(cur[c].x, cf, bs[c].x);
            o.y = fmaf(cur[c].y, cf, bs[c].y);
            o.z = fmaf(cur[c].z, cf, bs[c].z);
            o.w = fmaf(cur[c].w, cf, bs[c].w);
            __builtin_nontemporal_store(o,
                reinterpret_cast<f32x4*>(orow + c * 256 + off0));
        }

#pragma unroll
        for (int c = 0; c < 4; ++c) cur[c] = nxt[c];
    }
}

extern "C" void kernel_launch(void* const* d_in, const int* in_sizes, int n_in,
                              void* d_out, int out_size, void* d_ws, size_t ws_size,
                              hipStream_t stream)
{
    const float* x0 = (const float*)d_in[0];   // [16384, 1024]
    const float* W  = (const float*)d_in[1];   // [3, 1024]
    const float* B  = (const float*)d_in[2];   // [3, 1024]
    float* out      = (float*)d_out;           // [16384, 1024]

    dim3 grid(CN_BATCH / ROWS_PER_BLOCK);      // 1024 blocks, fully resident
    dim3 block(WAVES_PER_BLOCK * 64);          // 256
    crossnet_kernel<<<grid, block, 0, stream>>>(x0, W, B, out);
}

// Round 3
// 118.132 us; speedup vs baseline: 1.0622x; 1.0622x over previous
//
#include <hip/hip_runtime.h>

// CrossNet collapsed analytically:
//   a_j = x0 . w_j ; s0=a0 ; s1=(1+s0)a1 + t1 ; s2=(1+s0+s1)a2 + t2
//   out = x0*(1+s0+s1+s2) + bs
// where t1 = B0.w1, t2 = (B0+B1).w2, bs = B0+B1+B2 are ROW-INDEPENDENT:
// computed ONCE by a tiny pre-kernel into the workspace, so the main
// streaming kernel does 3 dots + ONE butterfly phase + 1 fused update/row.
// Plain (cache-friendly) loads/stores: x0 may be LLC-warm from the harness
// restore, and the 64 MiB output can be absorbed by the 256 MiB LLC.

#define CN_BATCH 16384
#define CN_DIM   1024

#define WAVES_PER_BLOCK 4
#define ROWS_PER_WAVE   2
#define ROWS_PER_BLOCK  (WAVES_PER_BLOCK * ROWS_PER_WAVE)   // 8
#define GRID_BLOCKS     (CN_BATCH / ROWS_PER_BLOCK)         // 2048

typedef float f32x4 __attribute__((ext_vector_type(4)));

__device__ __forceinline__ float fma4(f32x4 x, f32x4 w, float acc) {
    acc = fmaf(x.x, w.x, acc); acc = fmaf(x.y, w.y, acc);
    acc = fmaf(x.z, w.z, acc); acc = fmaf(x.w, w.w, acc);
    return acc;
}

// ---- pre-kernel: pre[0..1023] = B0+B1+B2 ; pre[1024]=B0.w1 ; pre[1025]=(B0+B1).w2
__global__ __launch_bounds__(256) void
crossnet_pre(const float* __restrict__ W, const float* __restrict__ B,
             float* __restrict__ pre)
{
    const int t    = threadIdx.x;          // 0..255, 4 floats each
    const int wave = t >> 6;
    const int lane = t & 63;

    const f32x4 b0 = *reinterpret_cast<const f32x4*>(B + 0 * CN_DIM + t * 4);
    const f32x4 b1 = *reinterpret_cast<const f32x4*>(B + 1 * CN_DIM + t * 4);
    const f32x4 b2 = *reinterpret_cast<const f32x4*>(B + 2 * CN_DIM + t * 4);
    const f32x4 w1 = *reinterpret_cast<const f32x4*>(W + 1 * CN_DIM + t * 4);
    const f32x4 w2 = *reinterpret_cast<const f32x4*>(W + 2 * CN_DIM + t * 4);

    *reinterpret_cast<f32x4*>(pre + t * 4) = b0 + b1 + b2;

    float p1 = fma4(b0, w1, 0.f);
    float p2 = fma4(b0 + b1, w2, 0.f);
#pragma unroll
    for (int o = 1; o < 64; o <<= 1) {
        p1 += __shfl_xor(p1, o, 64);
        p2 += __shfl_xor(p2, o, 64);
    }
    __shared__ float sh1[WAVES_PER_BLOCK], sh2[WAVES_PER_BLOCK];
    if (lane == 0) { sh1[wave] = p1; sh2[wave] = p2; }
    __syncthreads();
    if (t == 0) {
        pre[CN_DIM]     = sh1[0] + sh1[1] + sh1[2] + sh1[3];
        pre[CN_DIM + 1] = sh2[0] + sh2[1] + sh2[2] + sh2[3];
    }
}

// ---- main streaming kernel ----
template<bool PRE>
__global__ __launch_bounds__(256, 4) void
crossnet_main(const float* __restrict__ x0, const float* __restrict__ W,
              const float* __restrict__ B,  const float* __restrict__ pre,
              float* __restrict__ out)
{
    const int tid  = threadIdx.x;
    const int wave = tid >> 6;
    const int lane = tid & 63;
    const int off0 = lane * 4;             // 16B-aligned per-lane column

    const size_t row0 = ((size_t)blockIdx.x * WAVES_PER_BLOCK + wave) * ROWS_PER_WAVE;
    const float* __restrict__ xr = x0 + row0 * CN_DIM;

    // 1) issue ALL x loads up front (8 loads in flight per wave, HBM)
    f32x4 xv[ROWS_PER_WAVE][4];
#pragma unroll
    for (int r = 0; r < ROWS_PER_WAVE; ++r)
#pragma unroll
        for (int c = 0; c < 4; ++c)
            xv[r][c] = *reinterpret_cast<const f32x4*>(xr + r * CN_DIM + c * 256 + off0);

    // 2) row-independent constants: precomputed (L2-hot) or in-wave fallback
    f32x4 bs[4];
    float t1, t2;
    if (PRE) {
#pragma unroll
        for (int c = 0; c < 4; ++c)
            bs[c] = *reinterpret_cast<const f32x4*>(pre + c * 256 + off0);
        t1 = pre[CN_DIM];
        t2 = pre[CN_DIM + 1];
    } else {
        t1 = 0.f; t2 = 0.f;
#pragma unroll
        for (int c = 0; c < 4; ++c) {
            const int off = c * 256 + off0;
            const f32x4 b0 = *reinterpret_cast<const f32x4*>(B + 0 * CN_DIM + off);
            const f32x4 b1 = *reinterpret_cast<const f32x4*>(B + 1 * CN_DIM + off);
            const f32x4 b2 = *reinterpret_cast<const f32x4*>(B + 2 * CN_DIM + off);
            const f32x4 w1 = *reinterpret_cast<const f32x4*>(W + 1 * CN_DIM + off);
            const f32x4 w2 = *reinterpret_cast<const f32x4*>(W + 2 * CN_DIM + off);
            bs[c] = b0 + b1 + b2;
            t1 = fma4(b0, w1, t1);
            t2 = fma4(b0 + b1, w2, t2);
        }
#pragma unroll
        for (int o = 1; o < 64; o <<= 1) {
            t1 += __shfl_xor(t1, o, 64);
            t2 += __shfl_xor(t2, o, 64);
        }
    }

    // 3) three dots per row; each W chunk loaded once, shared by both rows
    float a[ROWS_PER_WAVE][3];
#pragma unroll
    for (int r = 0; r < ROWS_PER_WAVE; ++r) {
        a[r][0] = 0.f; a[r][1] = 0.f; a[r][2] = 0.f;
    }
#pragma unroll
    for (int c = 0; c < 4; ++c) {
        const int off = c * 256 + off0;
        const f32x4 w0 = *reinterpret_cast<const f32x4*>(W + 0 * CN_DIM + off);
        const f32x4 w1 = *reinterpret_cast<const f32x4*>(W + 1 * CN_DIM + off);
        const f32x4 w2 = *reinterpret_cast<const f32x4*>(W + 2 * CN_DIM + off);
#pragma unroll
        for (int r = 0; r < ROWS_PER_WAVE; ++r) {
            a[r][0] = fma4(xv[r][c], w0, a[r][0]);
            a[r][1] = fma4(xv[r][c], w1, a[r][1]);
            a[r][2] = fma4(xv[r][c], w2, a[r][2]);
        }
    }

    // 4) ONE butterfly phase: 6 independent chains (2 rows x 3 dots)
#pragma unroll
    for (int o = 1; o < 64; o <<= 1) {
#pragma unroll
        for (int r = 0; r < ROWS_PER_WAVE; ++r) {
            a[r][0] += __shfl_xor(a[r][0], o, 64);
            a[r][1] += __shfl_xor(a[r][1], o, 64);
            a[r][2] += __shfl_xor(a[r][2], o, 64);
        }
    }

    // 5) scalar combine + fused update/store
#pragma unroll
    for (int r = 0; r < ROWS_PER_WAVE; ++r) {
        const float s0 = a[r][0];
        const float s1 = fmaf(1.f + s0, a[r][1], t1);
        const float s2 = fmaf(1.f + s0 + s1, a[r][2], t2);
        const float cf = 1.f + s0 + s1 + s2;
        float* __restrict__ orow = out + (row0 + r) * CN_DIM;
#pragma unroll
        for (int c = 0; c < 4; ++c) {
            f32x4 o;
            o.x = fmaf(xv[r][c].x, cf, bs[c].x);
            o.y = fmaf(xv[r][c].y, cf, bs[c].y);
            o.z = fmaf(xv[r][c].z, cf, bs[c].z);
            o.w = fmaf(xv[r][c].w, cf, bs[c].w);
            *reinterpret_cast<f32x4*>(orow + c * 256 + off0) = o;
        }
    }
}

extern "C" void kernel_launch(void* const* d_in, const int* in_sizes, int n_in,
                              void* d_out, int out_size, void* d_ws, size_t ws_size,
                              hipStream_t stream)
{
    const float* x0 = (const float*)d_in[0];   // [16384, 1024]
    const float* W  = (const float*)d_in[1];   // [3, 1024]
    const float* B  = (const float*)d_in[2];   // [3, 1024]
    float* out      = (float*)d_out;           // [16384, 1024]

    dim3 grid(GRID_BLOCKS);                    // 2048 blocks
    dim3 block(WAVES_PER_BLOCK * 64);          // 256 threads

    if (d_ws != nullptr && ws_size >= (size_t)(CN_DIM + 2) * sizeof(float)) {
        float* pre = (float*)d_ws;
        crossnet_pre<<<dim3(1), dim3(256), 0, stream>>>(W, B, pre);
        crossnet_main<true><<<grid, block, 0, stream>>>(x0, W, B, pre, out);
    } else {
        crossnet_main<false><<<grid, block, 0, stream>>>(x0, W, B, nullptr, out);
    }
}

// Round 4
// 117.877 us; speedup vs baseline: 1.0645x; 1.0022x over previous
//
#include <hip/hip_runtime.h>

// CrossNet collapsed analytically:
//   a_j = x0 . w_j ; s0=a0 ; s1=(1+s0)a1 + t1 ; s2=(1+s0+s1)a2 + t2
//   out = x0*(1+s0+s1+s2) + bs
// t1 = B0.w1, t2 = (B0+B1).w2, bs = B0+B1+B2 are row-independent.
// SINGLE kernel (no serial pre-dispatch): each wave recomputes t1/t2/bs,
// but the B/W loads are L2-hot and issue inside the ~900-cycle latency
// shadow of the 8 in-flight HBM x-loads, and the two scalar reduction
// chains are FUSED into the same 6-stage butterfly as the six row-dot
// chains (8 independent chains, no extra depth).
// 2 rows/wave, 2048 blocks x 256 threads, plain cache-friendly loads/stores.

#define CN_BATCH 16384
#define CN_DIM   1024

#define WAVES_PER_BLOCK 4
#define ROWS_PER_WAVE   2
#define ROWS_PER_BLOCK  (WAVES_PER_BLOCK * ROWS_PER_WAVE)   // 8
#define GRID_BLOCKS     (CN_BATCH / ROWS_PER_BLOCK)         // 2048

typedef float f32x4 __attribute__((ext_vector_type(4)));

__device__ __forceinline__ float fma4(f32x4 x, f32x4 w, float acc) {
    acc = fmaf(x.x, w.x, acc); acc = fmaf(x.y, w.y, acc);
    acc = fmaf(x.z, w.z, acc); acc = fmaf(x.w, w.w, acc);
    return acc;
}

__global__ __launch_bounds__(256, 4) void
crossnet_kernel(const float* __restrict__ x0,
                const float* __restrict__ W,
                const float* __restrict__ B,
                float* __restrict__ out)
{
    const int tid  = threadIdx.x;
    const int wave = tid >> 6;
    const int lane = tid & 63;
    const int off0 = lane * 4;             // 16B-aligned per-lane column

    const size_t row0 = ((size_t)blockIdx.x * WAVES_PER_BLOCK + wave) * ROWS_PER_WAVE;
    const float* __restrict__ xr = x0 + row0 * CN_DIM;

    // 1) issue ALL x loads first (8 HBM loads in flight; longest latency leads)
    f32x4 xv[ROWS_PER_WAVE][4];
#pragma unroll
    for (int r = 0; r < ROWS_PER_WAVE; ++r)
#pragma unroll
        for (int c = 0; c < 4; ++c)
            xv[r][c] = *reinterpret_cast<const f32x4*>(xr + r * CN_DIM + c * 256 + off0);

    // 2) W/B loads (L2-hot, ~200cy) + scalar partials — all inside the
    //    latency shadow of the x loads (no dependence on xv).
    f32x4 w0[4], w1[4], w2[4], bs[4];
    float t1 = 0.f, t2 = 0.f;
#pragma unroll
    for (int c = 0; c < 4; ++c) {
        const int off = c * 256 + off0;
        w0[c] = *reinterpret_cast<const f32x4*>(W + 0 * CN_DIM + off);
        w1[c] = *reinterpret_cast<const f32x4*>(W + 1 * CN_DIM + off);
        w2[c] = *reinterpret_cast<const f32x4*>(W + 2 * CN_DIM + off);
        const f32x4 b0 = *reinterpret_cast<const f32x4*>(B + 0 * CN_DIM + off);
        const f32x4 b1 = *reinterpret_cast<const f32x4*>(B + 1 * CN_DIM + off);
        const f32x4 b2 = *reinterpret_cast<const f32x4*>(B + 2 * CN_DIM + off);
        bs[c] = b0 + b1 + b2;
        t1 = fma4(b0, w1[c], t1);
        t2 = fma4(b0 + b1, w2[c], t2);
    }

    // 3) row-dot partials (needs xv — first true consumer of the x loads)
    float a[ROWS_PER_WAVE][3];
#pragma unroll
    for (int r = 0; r < ROWS_PER_WAVE; ++r) {
        a[r][0] = 0.f; a[r][1] = 0.f; a[r][2] = 0.f;
    }
#pragma unroll
    for (int c = 0; c < 4; ++c) {
#pragma unroll
        for (int r = 0; r < ROWS_PER_WAVE; ++r) {
            a[r][0] = fma4(xv[r][c], w0[c], a[r][0]);
            a[r][1] = fma4(xv[r][c], w1[c], a[r][1]);
            a[r][2] = fma4(xv[r][c], w2[c], a[r][2]);
        }
    }

    // 4) ONE butterfly phase: 8 independent chains (2 rows x 3 dots + t1 + t2),
    //    6 stages, no added depth for the scalar chains.
#pragma unroll
    for (int o = 1; o < 64; o <<= 1) {
#pragma unroll
        for (int r = 0; r < ROWS_PER_WAVE; ++r) {
            a[r][0] += __shfl_xor(a[r][0], o, 64);
            a[r][1] += __shfl_xor(a[r][1], o, 64);
            a[r][2] += __shfl_xor(a[r][2], o, 64);
        }
        t1 += __shfl_xor(t1, o, 64);
        t2 += __shfl_xor(t2, o, 64);
    }

    // 5) scalar combine + fused update/store
#pragma unroll
    for (int r = 0; r < ROWS_PER_WAVE; ++r) {
        const float s0 = a[r][0];
        const float s1 = fmaf(1.f + s0, a[r][1], t1);
        const float s2 = fmaf(1.f + s0 + s1, a[r][2], t2);
        const float cf = 1.f + s0 + s1 + s2;
        float* __restrict__ orow = out + (row0 + r) * CN_DIM;
#pragma unroll
        for (int c = 0; c < 4; ++c) {
            f32x4 o;
            o.x = fmaf(xv[r][c].x, cf, bs[c].x);
            o.y = fmaf(xv[r][c].y, cf, bs[c].y);
            o.z = fmaf(xv[r][c].z, cf, bs[c].z);
            o.w = fmaf(xv[r][c].w, cf, bs[c].w);
            *reinterpret_cast<f32x4*>(orow + c * 256 + off0) = o;
        }
    }
}

extern "C" void kernel_launch(void* const* d_in, const int* in_sizes, int n_in,
                              void* d_out, int out_size, void* d_ws, size_t ws_size,
                              hipStream_t stream)
{
    const float* x0 = (const float*)d_in[0];   // [16384, 1024]
    const float* W  = (const float*)d_in[1];   // [3, 1024]
    const float* B  = (const float*)d_in[2];   // [3, 1024]
    float* out      = (float*)d_out;           // [16384, 1024]

    dim3 grid(GRID_BLOCKS);                    // 2048 blocks
    dim3 block(WAVES_PER_BLOCK * 64);          // 256 threads
    crossnet_kernel<<<grid, block, 0, stream>>>(x0, W, B, out);
}

// Round 5
// 116.164 us; speedup vs baseline: 1.0802x; 1.0147x over previous
//
#include <hip/hip_runtime.h>

// CrossNet collapsed analytically:
//   a_j = x0 . w_j ; s0=a0 ; s1=(1+s0)a1 + t1 ; s2=(1+s0+s1)a2 + t2
//   out = x0*(1+s0+s1+s2) + bs
// t1 = B0.w1, t2 = (B0+B1).w2, bs = B0+B1+B2 are row-independent.
//
// Persistent deep-pipelined version:
//  - 512 blocks x 256 thr = 2 blocks/CU, ALL resident at launch (no turnover).
//  - each wave owns 8 rows = 4 software-pipelined groups of 2 rows:
//    prefetch group g+1's x BEFORE reducing group g -> HBM queue never drains
//    during the butterfly/store tail.
//  - W/B loaded ONCE per wave (amortized over 8 rows); t1/t2 scalar chains
//    fused into group 0's butterfly (no extra reduction depth).
//  - plain cache-friendly loads/stores (nt hurt in round 2).

#define CN_BATCH 16384
#define CN_DIM   1024

#define WAVES_PER_BLOCK 4
#define GROUPS          4
#define GROUP_ROWS      2
#define ROWS_PER_WAVE   (GROUPS * GROUP_ROWS)                 // 8
#define ROWS_PER_BLOCK  (WAVES_PER_BLOCK * ROWS_PER_WAVE)     // 32
#define GRID_BLOCKS     (CN_BATCH / ROWS_PER_BLOCK)           // 512

typedef float f32x4 __attribute__((ext_vector_type(4)));

__device__ __forceinline__ float fma4(f32x4 x, f32x4 w, float acc) {
    acc = fmaf(x.x, w.x, acc); acc = fmaf(x.y, w.y, acc);
    acc = fmaf(x.z, w.z, acc); acc = fmaf(x.w, w.w, acc);
    return acc;
}

__global__ __launch_bounds__(256, 2) void
crossnet_kernel(const float* __restrict__ x0,
                const float* __restrict__ W,
                const float* __restrict__ B,
                float* __restrict__ out)
{
    const int tid  = threadIdx.x;
    const int wave = tid >> 6;
    const int lane = tid & 63;
    const int off0 = lane * 4;              // 16B-aligned per-lane column

    const size_t row0 = ((size_t)blockIdx.x * WAVES_PER_BLOCK + wave) * ROWS_PER_WAVE;
    const float* __restrict__ xr = x0 + row0 * CN_DIM;

    // ---- prologue: issue group-0 x loads FIRST (longest latency leads) ----
    f32x4 cur[GROUP_ROWS][4], nxt[GROUP_ROWS][4];
#pragma unroll
    for (int r = 0; r < GROUP_ROWS; ++r)
#pragma unroll
        for (int c = 0; c < 4; ++c)
            cur[r][c] = *reinterpret_cast<const f32x4*>(xr + r * CN_DIM + c * 256 + off0);

    // ---- W/B once per wave (L2-hot), inside the x-load shadow ----
    f32x4 w0[4], w1[4], w2[4], bs[4];
    float t1 = 0.f, t2 = 0.f;
#pragma unroll
    for (int c = 0; c < 4; ++c) {
        const int off = c * 256 + off0;
        w0[c] = *reinterpret_cast<const f32x4*>(W + 0 * CN_DIM + off);
        w1[c] = *reinterpret_cast<const f32x4*>(W + 1 * CN_DIM + off);
        w2[c] = *reinterpret_cast<const f32x4*>(W + 2 * CN_DIM + off);
        const f32x4 b0 = *reinterpret_cast<const f32x4*>(B + 0 * CN_DIM + off);
        const f32x4 b1 = *reinterpret_cast<const f32x4*>(B + 1 * CN_DIM + off);
        const f32x4 b2 = *reinterpret_cast<const f32x4*>(B + 2 * CN_DIM + off);
        bs[c] = b0 + b1 + b2;
        t1 = fma4(b0, w1[c], t1);
        t2 = fma4(b0 + b1, w2[c], t2);
    }

    // ---- 4 pipelined groups of 2 rows ----
#pragma unroll
    for (int g = 0; g < GROUPS; ++g) {
        // prefetch next group's x while we reduce/store the current one
        if (g + 1 < GROUPS) {
#pragma unroll
            for (int r = 0; r < GROUP_ROWS; ++r)
#pragma unroll
                for (int c = 0; c < 4; ++c)
                    nxt[r][c] = *reinterpret_cast<const f32x4*>(
                        xr + (size_t)((g + 1) * GROUP_ROWS + r) * CN_DIM + c * 256 + off0);
        }

        // three dot partials per row (W register-resident)
        float a[GROUP_ROWS][3];
#pragma unroll
        for (int r = 0; r < GROUP_ROWS; ++r) {
            a[r][0] = 0.f; a[r][1] = 0.f; a[r][2] = 0.f;
        }
#pragma unroll
        for (int c = 0; c < 4; ++c) {
#pragma unroll
            for (int r = 0; r < GROUP_ROWS; ++r) {
                a[r][0] = fma4(cur[r][c], w0[c], a[r][0]);
                a[r][1] = fma4(cur[r][c], w1[c], a[r][1]);
                a[r][2] = fma4(cur[r][c], w2[c], a[r][2]);
            }
        }

        // ONE butterfly phase: 6 chains (+ t1,t2 fused on the first group)
#pragma unroll
        for (int o = 1; o < 64; o <<= 1) {
#pragma unroll
            for (int r = 0; r < GROUP_ROWS; ++r) {
                a[r][0] += __shfl_xor(a[r][0], o, 64);
                a[r][1] += __shfl_xor(a[r][1], o, 64);
                a[r][2] += __shfl_xor(a[r][2], o, 64);
            }
            if (g == 0) {
                t1 += __shfl_xor(t1, o, 64);
                t2 += __shfl_xor(t2, o, 64);
            }
        }

        // scalar combine + fused update/store
#pragma unroll
        for (int r = 0; r < GROUP_ROWS; ++r) {
            const float s0 = a[r][0];
            const float s1 = fmaf(1.f + s0, a[r][1], t1);
            const float s2 = fmaf(1.f + s0 + s1, a[r][2], t2);
            const float cf = 1.f + s0 + s1 + s2;
            float* __restrict__ orow = out + (row0 + (size_t)(g * GROUP_ROWS + r)) * CN_DIM;
#pragma unroll
            for (int c = 0; c < 4; ++c) {
                f32x4 o;
                o.x = fmaf(cur[r][c].x, cf, bs[c].x);
                o.y = fmaf(cur[r][c].y, cf, bs[c].y);
                o.z = fmaf(cur[r][c].z, cf, bs[c].z);
                o.w = fmaf(cur[r][c].w, cf, bs[c].w);
                *reinterpret_cast<f32x4*>(orow + c * 256 + off0) = o;
            }
        }

        // rotate pipeline
#pragma unroll
        for (int r = 0; r < GROUP_ROWS; ++r)
#pragma unroll
            for (int c = 0; c < 4; ++c)
                cur[r][c] = nxt[r][c];
    }
}

extern "C" void kernel_launch(void* const* d_in, const int* in_sizes, int n_in,
                              void* d_out, int out_size, void* d_ws, size_t ws_size,
                              hipStream_t stream)
{
    const float* x0 = (const float*)d_in[0];   // [16384, 1024]
    const float* W  = (const float*)d_in[1];   // [3, 1024]
    const float* B  = (const float*)d_in[2];   // [3, 1024]
    float* out      = (float*)d_out;           // [16384, 1024]

    dim3 grid(GRID_BLOCKS);                    // 512 blocks = 2 blocks/CU, all resident
    dim3 block(WAVES_PER_BLOCK * 64);          // 256 threads
    crossnet_kernel<<<grid, block, 0, stream>>>(x0, W, B, out);
}